// Round 1
// baseline (425.929 us; speedup 1.0000x reference)
//
#include <hip/hip_runtime.h>

#define BB   128
#define SSZ  8
#define FF   32
#define OOUT 16
#define DDIM 15

// One block per (x,y,X,Y). Stage W[dx,dy] (16x32x32 fp32 = 64 KB) in LDS as
// [i][j][o] so the inner loop reads 8 consecutive o's as two float4 broadcasts.
__global__ __launch_bounds__(256, 2) void rel_bilinear_f32(
    const float* __restrict__ inp,
    const float* __restrict__ W,
    const float* __restrict__ bias,
    float* __restrict__ out)
{
    __shared__ float Wl[FF * FF * OOUT]; // [i][j][o] : 65536 B

    const int bid = blockIdx.x;
    const int Y = bid & 7;
    const int X = (bid >> 3) & 7;
    const int y = (bid >> 6) & 7;
    const int x = (bid >> 9) & 7;
    const int dx = X - x + (SSZ - 1);
    const int dy = Y - y + (SSZ - 1);

    const float* Wg = W + (size_t)(dx * DDIM + dy) * (OOUT * FF * FF); // W[dx][dy][o][i][j]

    const int t = threadIdx.x;

    // ---- stage W[dx][dy] -> LDS [i][j][o]; lanes span o => bank-conflict-free writes ----
    {
        const int o = t & 15;      // lanes 0..15 of each 16-group cover o
        const int u = t >> 4;      // 0..15
        #pragma unroll 1
        for (int batch = 0; batch < 4; ++batch) {
            float v[16];
            #pragma unroll
            for (int q = 0; q < 16; ++q) {       // 16 outstanding loads
                const int it = batch * 16 + q;   // 0..63
                const int i = it >> 1;
                const int j = u + ((it & 1) << 4);
                v[q] = Wg[o * (FF * FF) + i * FF + j];
            }
            #pragma unroll
            for (int q = 0; q < 16; ++q) {
                const int it = batch * 16 + q;
                const int i = it >> 1;
                const int j = u + ((it & 1) << 4);
                Wl[(i * FF + j) * OOUT + o] = v[q];
            }
        }
    }
    __syncthreads();

    // ---- compute: thread = (b, o-half) ----
    const int b  = t >> 1;
    const int o0 = (t & 1) << 3;

    const float* arow = inp + ((b * SSZ + x) * SSZ + y) * FF; // inp[b,x,y,:]
    const float* crow = inp + ((b * SSZ + X) * SSZ + Y) * FF; // inp[b,X,Y,:]

    float c[FF];
    #pragma unroll
    for (int j4 = 0; j4 < FF / 4; ++j4) {
        const float4 v = ((const float4*)crow)[j4];
        c[j4 * 4 + 0] = v.x; c[j4 * 4 + 1] = v.y;
        c[j4 * 4 + 2] = v.z; c[j4 * 4 + 3] = v.w;
    }

    float acc[8];
    #pragma unroll
    for (int k = 0; k < 8; ++k) acc[k] = 0.f;

    float ai_next = arow[0];
    #pragma unroll 1
    for (int i = 0; i < FF; ++i) {
        const float ai = ai_next;
        ai_next = arow[(i + 1) & (FF - 1)];  // prefetch next a[i] (L1), latency hidden by j-loop
        const float* wrow = &Wl[(i * FF) * OOUT + o0];
        #pragma unroll
        for (int j = 0; j < FF; ++j) {
            const float p = ai * c[j];
            const float4 w0 = *(const float4*)(wrow + j * OOUT);
            const float4 w1 = *(const float4*)(wrow + j * OOUT + 4);
            acc[0] = fmaf(w0.x, p, acc[0]);
            acc[1] = fmaf(w0.y, p, acc[1]);
            acc[2] = fmaf(w0.z, p, acc[2]);
            acc[3] = fmaf(w0.w, p, acc[3]);
            acc[4] = fmaf(w1.x, p, acc[4]);
            acc[5] = fmaf(w1.y, p, acc[5]);
            acc[6] = fmaf(w1.z, p, acc[6]);
            acc[7] = fmaf(w1.w, p, acc[7]);
        }
    }

    // ---- bias (note reference transpose: out[b,x,y,X,Y,o] += bias[dx,dy,o]) + store ----
    const float* bptr = bias + (dx * DDIM + dy) * OOUT + o0;
    #pragma unroll
    for (int k = 0; k < 8; ++k) acc[k] += bptr[k];

    float* op = out + (((((size_t)b * SSZ + x) * SSZ + y) * SSZ + X) * SSZ + Y) * OOUT + o0;
    *(float4*)(op)     = make_float4(acc[0], acc[1], acc[2], acc[3]);
    *(float4*)(op + 4) = make_float4(acc[4], acc[5], acc[6], acc[7]);
}

extern "C" void kernel_launch(void* const* d_in, const int* in_sizes, int n_in,
                              void* d_out, int out_size, void* d_ws, size_t ws_size,
                              hipStream_t stream)
{
    const float* inp  = (const float*)d_in[0]; // (128,8,8,32) fp32
    const float* W    = (const float*)d_in[1]; // (15,15,16,32,32) fp32
    const float* bias = (const float*)d_in[2]; // (15,15,16) fp32
    float* out = (float*)d_out;                // (128,8,8,8,8,16) fp32

    dim3 grid(SSZ * SSZ * SSZ * SSZ); // 4096 blocks: (x,y,X,Y)
    dim3 block(256);
    hipLaunchKernelGGL(rel_bilinear_f32, grid, block, 0, stream, inp, W, bias, out);
}

// Round 2
// 114.738 us; speedup vs baseline: 3.7122x; 3.7122x over previous
//
#include <hip/hip_runtime.h>

typedef _Float16 f16;
typedef _Float16 f16x8 __attribute__((ext_vector_type(8)));
typedef _Float16 f16x4 __attribute__((ext_vector_type(4)));
typedef float f32x4 __attribute__((ext_vector_type(4)));

#define LDS_OSTRIDE 1032   // halves; pad 32*32+8 so o-stride*2/4 = 516 dwords -> 4*(o) bank rotation
#define W4 921600          // W float4 count (15*15*16*32*32 / 4)
#define I4 65536           // inp float4 count (128*8*8*32 / 4)

// ---- fp32 -> f16 conversion of W and inp into workspace ----
__global__ __launch_bounds__(256) void convert_kernel(
    const float* __restrict__ W, const float* __restrict__ inp,
    f16* __restrict__ W_h, f16* __restrict__ inp_h)
{
    const int idx = blockIdx.x * 256 + threadIdx.x;   // float4 index, grid sized exactly
    if (idx < W4) {
        const float4 v = ((const float4*)W)[idx];
        f16x4 h = { (f16)v.x, (f16)v.y, (f16)v.z, (f16)v.w };
        *(f16x4*)(W_h + (size_t)idx * 4) = h;
    } else {
        const int k = idx - W4;
        const float4 v = ((const float4*)inp)[k];
        f16x4 h = { (f16)v.x, (f16)v.y, (f16)v.z, (f16)v.w };
        *(f16x4*)(inp_h + (size_t)k * 4) = h;
    }
}

// One block per (x,y,X,Y). out[b,o] = sum_k P[b,k] * Wf[k,o], k=(i,j), K=1024.
// A-frag on the fly: a[b,kb] * c[b, quad*8+r]  (4 pk_mul per fragment).
// B-frag: 16 contiguous bytes of LDS-staged W[o][i][j] (padded o-stride).
template <int HALFSRC>
__global__ __launch_bounds__(256, 4) void rel_mfma(
    const void* __restrict__ Wsrc, const void* __restrict__ isrc,
    const float* __restrict__ bias, float* __restrict__ out)
{
    __shared__ f16 Wl[16 * LDS_OSTRIDE];   // 33,024 B -> 4 blocks/CU

    const int bid = blockIdx.x;
    const int Y = bid & 7, X = (bid >> 3) & 7, y = (bid >> 6) & 7, x = (bid >> 9) & 7;
    const int dx = X - x + 7, dy = Y - y + 7;
    const size_t woff = (size_t)(dx * 15 + dy) * 16384;   // W block [o][i][j], 16*32*32

    const int t = threadIdx.x;

    // ---- stage W[dx,dy] -> LDS; lanes span o so LDS writes are bank-uniform ----
    {
        const int o = t & 15;
        const int r = t >> 4;
        if (HALFSRC) {
            const f16* Wg = (const f16*)Wsrc + woff + o * 1024;
            #pragma unroll
            for (int it = 0; it < 8; ++it) {
                const int within = r + it * 16;            // 0..127 chunks of 8 halves
                f16x8 v = *(const f16x8*)(Wg + within * 8);
                *(f16x8*)(&Wl[o * LDS_OSTRIDE + within * 8]) = v;
            }
        } else {
            const float* Wg = (const float*)Wsrc + woff + o * 1024;
            #pragma unroll
            for (int it = 0; it < 8; ++it) {
                const int within = r + it * 16;
                const float4 v0 = *(const float4*)(Wg + within * 8);
                const float4 v1 = *(const float4*)(Wg + within * 8 + 4);
                f16x8 h = { (f16)v0.x, (f16)v0.y, (f16)v0.z, (f16)v0.w,
                            (f16)v1.x, (f16)v1.y, (f16)v1.z, (f16)v1.w };
                *(f16x8*)(&Wl[o * LDS_OSTRIDE + within * 8]) = h;
            }
        }
    }

    const int lane = t & 63;
    const int wave = t >> 6;       // 0..3, handles b-tiles 2w, 2w+1
    const int quad = lane >> 4;
    const int m = lane & 15;       // A-row (b_local) AND B-col (o) lane index

    // ---- per-lane a rows (32 halves each) and c fragments ----
    f16x8 a0[4], a1[4], c0, c1;
    {
        const int b0 = wave * 32 + m;
        const int b1 = b0 + 16;
        if (HALFSRC) {
            const f16* ih = (const f16*)isrc;
            const f16* ar0 = ih + ((b0 * 8 + x) * 8 + y) * 32;
            const f16* ar1 = ih + ((b1 * 8 + x) * 8 + y) * 32;
            #pragma unroll
            for (int g = 0; g < 4; ++g) {
                a0[g] = *(const f16x8*)(ar0 + g * 8);
                a1[g] = *(const f16x8*)(ar1 + g * 8);
            }
            c0 = *(const f16x8*)(ih + ((b0 * 8 + X) * 8 + Y) * 32 + quad * 8);
            c1 = *(const f16x8*)(ih + ((b1 * 8 + X) * 8 + Y) * 32 + quad * 8);
        } else {
            const float* is = (const float*)isrc;
            const float* ar0 = is + ((b0 * 8 + x) * 8 + y) * 32;
            const float* ar1 = is + ((b1 * 8 + x) * 8 + y) * 32;
            #pragma unroll
            for (int g = 0; g < 4; ++g)
                #pragma unroll
                for (int u = 0; u < 8; ++u) {
                    a0[g][u] = (f16)ar0[g * 8 + u];
                    a1[g][u] = (f16)ar1[g * 8 + u];
                }
            const float* cr0 = is + ((b0 * 8 + X) * 8 + Y) * 32 + quad * 8;
            const float* cr1 = is + ((b1 * 8 + X) * 8 + Y) * 32 + quad * 8;
            #pragma unroll
            for (int u = 0; u < 8; ++u) { c0[u] = (f16)cr0[u]; c1[u] = (f16)cr1[u]; }
        }
    }

    __syncthreads();

    // ---- K-loop: 32 steps, B-frag shared by both b-tiles ----
    f32x4 acc0 = {0.f, 0.f, 0.f, 0.f};
    f32x4 acc1 = {0.f, 0.f, 0.f, 0.f};
    const f16* wl = &Wl[m * LDS_OSTRIDE + quad * 8];
    #pragma unroll
    for (int g = 0; g < 4; ++g) {
        #pragma unroll
        for (int u = 0; u < 8; ++u) {
            const int kb = g * 8 + u;                       // = i
            f16x8 bfrag = *(const f16x8*)(wl + kb * 32);    // W[o, kb, quad*8 + 0..7]
            f16x8 af0 = c0 * a0[g][u];                      // P[b, kb*32 + quad*8 + r]
            f16x8 af1 = c1 * a1[g][u];
            acc0 = __builtin_amdgcn_mfma_f32_16x16x32_f16(af0, bfrag, acc0, 0, 0, 0);
            acc1 = __builtin_amdgcn_mfma_f32_16x16x32_f16(af1, bfrag, acc1, 0, 0, 0);
        }
    }

    // ---- epilogue: C layout col=o=lane&15, row=b_local=quad*4+reg ----
    const float bv = bias[(dx * 15 + dy) * 16 + m];
    #pragma unroll
    for (int r = 0; r < 4; ++r) {
        const int b0 = wave * 32 + quad * 4 + r;
        const int b1 = b0 + 16;
        out[((size_t)b0 * 4096 + bid) * 16 + m] = acc0[r] + bv;
        out[((size_t)b1 * 4096 + bid) * 16 + m] = acc1[r] + bv;
    }
}

extern "C" void kernel_launch(void* const* d_in, const int* in_sizes, int n_in,
                              void* d_out, int out_size, void* d_ws, size_t ws_size,
                              hipStream_t stream)
{
    const float* inp  = (const float*)d_in[0];  // (128,8,8,32)
    const float* W    = (const float*)d_in[1];  // (15,15,16,32,32)
    const float* bias = (const float*)d_in[2];  // (15,15,16)
    float* out = (float*)d_out;                 // (128,8,8,8,8,16)

    const size_t W_H_BYTES   = (size_t)W4 * 4 * sizeof(f16);  // 14,745,600
    const size_t INP_H_BYTES = (size_t)I4 * 4 * sizeof(f16);  //    524,288

    if (ws_size >= W_H_BYTES + INP_H_BYTES) {
        f16* W_h   = (f16*)d_ws;
        f16* inp_h = (f16*)((char*)d_ws + W_H_BYTES);
        hipLaunchKernelGGL(convert_kernel, dim3((W4 + I4) / 256), dim3(256), 0, stream,
                           W, inp, W_h, inp_h);
        hipLaunchKernelGGL((rel_mfma<1>), dim3(4096), dim3(256), 0, stream,
                           (const void*)W_h, (const void*)inp_h, bias, out);
    } else {
        // ws too small: stage fp32 W directly, convert in-kernel (slower, correct)
        hipLaunchKernelGGL((rel_mfma<0>), dim3(4096), dim3(256), 0, stream,
                           (const void*)W, (const void*)inp, bias, out);
    }
}